// Round 5
// baseline (1409.115 us; speedup 1.0000x reference)
//
#include <hip/hip_runtime.h>

#define B_    128
#define T_    720
#define C_    862
#define SEG   48
#define NSEG  15
#define O_    256
#define NCH   14             // ceil(862/64) c-chunks
#define NBLK  (NSEG * NCH)   // 210 blocks
#define NSLOT 42             // 210 % 42 == 0 -> 5 blocks per slot

typedef __attribute__((ext_vector_type(8))) short bf16x8;
typedef __attribute__((ext_vector_type(4))) float f32x4;
typedef __attribute__((ext_vector_type(2))) float f2v;

// round-to-nearest-even f32 -> bf16 (inputs finite)
static __device__ inline unsigned int f2bf(float f) {
    unsigned int u = __float_as_uint(f);
    return (u + 0x7fffu + ((u >> 16) & 1u)) >> 16;
}

__global__ __launch_bounds__(256) void zero_kernel(float* __restrict__ p, int n) {
    int i = blockIdx.x * 256 + threadIdx.x;
    if (i < n) p[i] = 0.f;
}

// bsum[o] = sum_c bias[c][o]
__global__ __launch_bounds__(256) void bias_kernel(const float* __restrict__ bias,
                                                   float* __restrict__ bsum) {
    int o  = threadIdx.x;
    int c0 = blockIdx.x * 27;
    float s = 0.f;
    for (int c = c0; c < c0 + 27 && c < C_; ++c) s += bias[(long)c * O_ + o];
    atomicAdd(bsum + o, s);
}

// One WG per (segment, c-chunk): all 48 t's of the segment, 64 c's, M=128(b),
// N=256(o). Main loop: acc += bf16(x) * bf16(W) over (t,c) with RAW x (no mean
// subtraction); meanwhile msum[b,c] (staging regs) and wsum[k,o] (per-lane
// regs) accumulate. Epilogue applies the segment-norm correction
// acc += (-msum/48) * wsum via 32 MFMAs, then atomics into accbuf slot.
// x and W are each read from HBM exactly once (954 MB total).
__global__ __launch_bounds__(512, 2) void gemm_kernel(const float* __restrict__ x,
                                                      const float* __restrict__ W,
                                                      float* __restrict__ accbuf) {
    __shared__ unsigned int A_lds[2][128 * 64 / 2];   // 2 x 16 KB (128 rows x 64 bf16)

    const int bid = blockIdx.x;
    const int s   = bid / NCH;          // segment
    const int c0  = (bid % NCH) * 64;   // c-chunk base
    const int tb  = s * SEG;            // first t of segment
    float* acc_out = accbuf + (long)(bid % NSLOT) * (B_ * O_);

    const int tid  = threadIdx.x;
    const int lane = tid & 63;
    const int w    = tid >> 6;
    const int wm   = w >> 2;            // 0..1 : b0 = wm*64
    const int wn   = w & 3;             // 0..3 : o0 = wn*64

    // staging geometry (fixed per thread): 8 rows x one float2-column
    const int srow = tid >> 5;          // row = srow + j*16
    const int sc2  = tid & 31;          // float2 col within 64-c chunk
    const int cme  = c0 + sc2 * 2;      // this thread's c (fixed)

    f32x4 acc[4][4] = {};               // [mi][ni] : wave tile 64(b) x 64(o)
    f2v   xv[8];
    float msum[8][2] = {};              // segment x-sums for this thread's (rows, c-pair)
    float wsum[2][4][8] = {};           // [ks][ni][j] : sum_t W for this lane's (k,o)
    float wpre[8];                      // prefetched W (ks=0, ni=0) for next t

    const int kb0 = c0 + (lane >> 4) * 8;       // lane's k-base, ks=0
    const int ome = wn * 64 + (lane & 15);      // lane's o (ni=0)

    auto load_x = [&](int tn) {
        #pragma unroll
        for (int j = 0; j < 8; ++j) {
            int row = srow + j * 16;
            xv[j] = (cme < C_)
                ? __builtin_nontemporal_load(
                      reinterpret_cast<const f2v*>(x + ((long)row * T_ + tn) * C_ + cme))
                : (f2v)0.f;
        }
    };

    auto load_wpre = [&](int tn) {
        const float* wp = W + ((long)kb0 * T_ + tn) * O_ + ome;
        #pragma unroll
        for (int j = 0; j < 8; ++j)
            wpre[j] = (kb0 + j < C_)
                ? __builtin_nontemporal_load(wp + (long)j * (T_ * O_)) : 0.f;
    };

    auto pack_write = [&](int bufi) {   // stage xv -> LDS bf16, accumulate msum
        unsigned int* Lb = A_lds[bufi];
        #pragma unroll
        for (int j = 0; j < 8; ++j) {
            int row = srow + j * 16;
            msum[j][0] += xv[j][0];
            msum[j][1] += xv[j][1];
            unsigned int pk = f2bf(xv[j][0]) | (f2bf(xv[j][1]) << 16);
            int byte = row * 128 + ((sc2 * 4) ^ ((row & 7) << 4));
            Lb[byte >> 2] = pk;
        }
    };

    auto read_af = [&](const unsigned int* Lb, int ks, bf16x8* af) {
        #pragma unroll
        for (int mi = 0; mi < 4; ++mi) {
            int row  = wm * 64 + mi * 16 + (lane & 15);
            int byte = row * 128 + ((ks * 64 + (lane >> 4) * 16) ^ ((row & 7) << 4));
            af[mi] = *reinterpret_cast<const bf16x8*>(
                         reinterpret_cast<const char*>(Lb) + byte);
        }
    };

    // prologue: stage t=tb, prefetch its first W slice
    load_x(tb);
    load_wpre(tb);
    pack_write(0);
    __syncthreads();

    for (int i = 0; i < SEG; ++i) {
        const int t = tb + i;
        const int cbuf = i & 1;
        const bool has_next = (i + 1 < SEG);
        const unsigned int* Lb = A_lds[cbuf];
        bf16x8 af[4];

        // ---- ks = 0, ni = 0 : runs off the prefetched W slice ----
        read_af(Lb, 0, af);
        bf16x8 b0;
        #pragma unroll
        for (int j = 0; j < 8; ++j) {
            wsum[0][0][j] += wpre[j];
            b0[j] = (short)f2bf(wpre[j]);
        }
        if (has_next) load_x(t + 1);          // issue next t's x loads early
        #pragma unroll
        for (int mi = 0; mi < 4; ++mi)
            acc[mi][0] = __builtin_amdgcn_mfma_f32_16x16x32_bf16(af[mi], b0, acc[mi][0], 0, 0, 0);
        if (has_next) load_wpre(t + 1);       // wpre consumed -> safe to reload

        // ---- ks = 0, ni = 1..3 ----
        #pragma unroll
        for (int ni = 1; ni < 4; ++ni) {
            const float* wp = W + ((long)kb0 * T_ + t) * O_ + (ome + ni * 16);
            bf16x8 bf;
            #pragma unroll
            for (int j = 0; j < 8; ++j) {
                float v = (kb0 + j < C_)
                    ? __builtin_nontemporal_load(wp + (long)j * (T_ * O_)) : 0.f;
                wsum[0][ni][j] += v;
                bf[j] = (short)f2bf(v);
            }
            #pragma unroll
            for (int mi = 0; mi < 4; ++mi)
                acc[mi][ni] = __builtin_amdgcn_mfma_f32_16x16x32_bf16(af[mi], bf, acc[mi][ni], 0, 0, 0);
        }

        // ---- ks = 1, ni = 0..3 ----
        read_af(Lb, 1, af);
        #pragma unroll
        for (int ni = 0; ni < 4; ++ni) {
            const float* wp = W + ((long)(kb0 + 32) * T_ + t) * O_ + (ome + ni * 16);
            bf16x8 bf;
            #pragma unroll
            for (int j = 0; j < 8; ++j) {
                float v = (kb0 + 32 + j < C_)
                    ? __builtin_nontemporal_load(wp + (long)j * (T_ * O_)) : 0.f;
                wsum[1][ni][j] += v;
                bf[j] = (short)f2bf(v);
            }
            #pragma unroll
            for (int mi = 0; mi < 4; ++mi)
                acc[mi][ni] = __builtin_amdgcn_mfma_f32_16x16x32_bf16(af[mi], bf, acc[mi][ni], 0, 0, 0);
        }

        if (has_next) pack_write(cbuf ^ 1);   // write late, other buffer
        __syncthreads();                      // single barrier per t
    }

    // ---- segment-norm correction: acc += (-msum/48) * wsum ----
    {
        unsigned int* Lb = A_lds[0];
        #pragma unroll
        for (int j = 0; j < 8; ++j) {
            int row = srow + j * 16;
            unsigned int pk = f2bf(msum[j][0] * (-1.f / SEG))
                            | (f2bf(msum[j][1] * (-1.f / SEG)) << 16);
            int byte = row * 128 + ((sc2 * 4) ^ ((row & 7) << 4));
            Lb[byte >> 2] = pk;
        }
    }
    __syncthreads();
    #pragma unroll
    for (int ks = 0; ks < 2; ++ks) {
        bf16x8 af[4];
        read_af(A_lds[0], ks, af);
        #pragma unroll
        for (int ni = 0; ni < 4; ++ni) {
            bf16x8 bw;
            #pragma unroll
            for (int j = 0; j < 8; ++j) bw[j] = (short)f2bf(wsum[ks][ni][j]);
            #pragma unroll
            for (int mi = 0; mi < 4; ++mi)
                acc[mi][ni] = __builtin_amdgcn_mfma_f32_16x16x32_bf16(af[mi], bw, acc[mi][ni], 0, 0, 0);
        }
    }

    // epilogue: one atomic per output element per block.
    // C/D layout: col(o) = lane&15, row(b) = (lane>>4)*4 + r
    #pragma unroll
    for (int mi = 0; mi < 4; ++mi)
        #pragma unroll
        for (int ni = 0; ni < 4; ++ni)
            #pragma unroll
            for (int r = 0; r < 4; ++r) {
                int row = wm * 64 + mi * 16 + (lane >> 4) * 4 + r;
                int o   = wn * 64 + ni * 16 + (lane & 15);
                atomicAdd(acc_out + (long)row * O_ + o, acc[mi][ni][r]);
            }
}

// out[b][o] = (sum_slots acc + bias_sum[o]) / C
__global__ __launch_bounds__(256) void final_kernel(const float* __restrict__ accbuf,
                                                    const float* __restrict__ bsum,
                                                    float* __restrict__ out) {
    int b = blockIdx.x, o = threadIdx.x;
    float sum = bsum[o];
    #pragma unroll 7
    for (int g = 0; g < NSLOT; ++g)
        sum += accbuf[(long)g * (B_ * O_) + (long)b * O_ + o];
    out[(long)b * O_ + o] = sum * (1.f / C_);
}

extern "C" void kernel_launch(void* const* d_in, const int* in_sizes, int n_in,
                              void* d_out, int out_size, void* d_ws, size_t ws_size,
                              hipStream_t stream) {
    const float* x    = (const float*)d_in[0];
    const float* W    = (const float*)d_in[1];
    const float* bias = (const float*)d_in[2];
    float* out = (float*)d_out;

    float* ws     = (float*)d_ws;
    float* accbuf = ws;                          // NSLOT * 128 * 256 floats = 5.5 MB
    float* bsum   = ws + (long)NSLOT * B_ * O_;  // 256 floats

    int nz = NSLOT * B_ * O_ + O_;
    zero_kernel<<<(nz + 255) / 256, 256, 0, stream>>>(accbuf, nz);
    bias_kernel<<<32, 256, 0, stream>>>(bias, bsum);
    gemm_kernel<<<NBLK, 512, 0, stream>>>(x, W, accbuf);
    final_kernel<<<B_, 256, 0, stream>>>(accbuf, bsum, out);
}